// Round 1
// baseline (922.454 us; speedup 1.0000x reference)
//
#include <hip/hip_runtime.h>
#include <hip/hip_bf16.h>

#define Hn 8
#define Fn 768
#define Dn 128
#define En 256
#define Ln 13
#define Bn 8
#define Tn 1000
#define TPn 1024
#define NCOR 8128

typedef float f32x4 __attribute__((ext_vector_type(4)));
typedef __bf16 bf16x8 __attribute__((ext_vector_type(8)));
typedef unsigned short u16;

static __device__ __forceinline__ u16 f2bf(float f) {
  __hip_bfloat16 h = __float2bfloat16(f);
  return __builtin_bit_cast(u16, h);
}
static __device__ __forceinline__ float bf2f(u16 u) {
  return __bfloat162float(__builtin_bit_cast(__hip_bfloat16, u));
}

// ---------------------------------------------------------------- k0: prep
// softmax(weights) -> kvw ; Wk/Wv -> bf16 ; zero stats accumulators
__global__ __launch_bounds__(256) void k0_prep(
    const float* __restrict__ wk, const float* __restrict__ wv,
    const float* __restrict__ Wk, const float* __restrict__ Wv,
    float* __restrict__ kvw, u16* __restrict__ Wbf,
    float* __restrict__ s1, float* __restrict__ s2) {
  int gid = blockIdx.x * 256 + threadIdx.x;
  if (gid < 16) {
    int kv = gid >> 3, h = gid & 7;
    const float* w = (kv ? wv : wk) + h * Ln;
    float m = -1e30f;
    for (int l = 0; l < Ln; ++l) m = fmaxf(m, w[l]);
    float e[Ln], s = 0.f;
    for (int l = 0; l < Ln; ++l) { e[l] = expf(w[l] - m); s += e[l]; }
    for (int l = 0; l < Ln; ++l) kvw[(kv * Hn + h) * Ln + l] = e[l] / s;
  }
  int n = 2 * Hn * Dn * Fn;
  for (int i = gid; i < n; i += gridDim.x * 256) {
    float v = (i < Hn * Dn * Fn) ? Wk[i] : Wv[i - Hn * Dn * Fn];
    Wbf[i] = f2bf(v);
  }
  int ns = 2 * Bn * Hn * Dn;
  for (int i = gid; i < ns; i += gridDim.x * 256) { s1[i] = 0.f; s2[i] = 0.f; }
}

// ---------------------------------------------------------------- k1: l-reduce
// x (B,F,T,L) fp32 -> kv_raw [kv][b_l][h][t][f] bf16 (f contiguous)
// block = (f-chunk 32, t-tile 32, b). LDS transpose for coalesced writes.
__global__ __launch_bounds__(256) void k1_raw(
    const float* __restrict__ x, const float* __restrict__ kvw_g,
    u16* __restrict__ kv_raw, int b0, int BG) {
  __shared__ float kvw[16 * Ln];
  __shared__ u16 res[16 * 32 * 34];  // [o][t][f+pad]; 17*t mod 32 -> conflict-free
  int tid = threadIdx.x;
  if (tid < 16 * Ln) kvw[tid] = kvw_g[tid];
  __syncthreads();
  int f0 = blockIdx.x * 32, t0 = blockIdx.y * 32;
  int b_l = blockIdx.z, b = b0 + b_l;
#pragma unroll
  for (int k = 0; k < 4; ++k) {
    int p = tid + k * 256;
    int tl = p & 31, fl = p >> 5;  // t fastest -> coalesced x reads
    int t = t0 + tl;
    if (t < Tn) {
      const float* xp = x + ((size_t)(b * Fn + f0 + fl) * Tn + t) * Ln;
      float xv[Ln];
#pragma unroll
      for (int l = 0; l < Ln; ++l) xv[l] = xp[l];
#pragma unroll
      for (int o = 0; o < 16; ++o) {
        float a = 0.f;
#pragma unroll
        for (int l = 0; l < Ln; ++l) a += xv[l] * kvw[o * Ln + l];
        res[o * 1088 + tl * 34 + fl] = f2bf(a);
      }
    }
  }
  __syncthreads();
  for (int rr = tid; rr < 512; rr += 256) {
    int o = rr >> 5, tl = rr & 31;
    int t = t0 + tl;
    if (t >= Tn) continue;
    int kv = o >> 3, h = o & 7;
    u16* dst = kv_raw + (((size_t)(kv * BG + b_l) * Hn + h) * TPn + t) * Fn + f0;
    const u16* src = res + o * 1088 + tl * 34;
#pragma unroll
    for (int i = 0; i < 4; ++i) {
      uint4 v;
      v.x = *(const unsigned int*)(src + 8 * i + 0);
      v.y = *(const unsigned int*)(src + 8 * i + 2);
      v.z = *(const unsigned int*)(src + 8 * i + 4);
      v.w = *(const unsigned int*)(src + 8 * i + 6);
      *reinterpret_cast<uint4*>(dst + 8 * i) = v;
    }
  }
}

// ---------------------------------------------------------------- k2: main GEMM
// mh[t][d] = kv_raw[t][:] . W[d][:] + bias.  128x128 tile, BK=32, bf16 MFMA.
// Stores mh TRANSPOSED as bf16 [kv][b][h][d][t_pad] (zeros for t>=Tn) and
// accumulates per-d sum/sumsq of the bf16-rounded values (consistency w/ k4).
__global__ __launch_bounds__(256) void k2_gemm(
    const u16* __restrict__ kv_raw, const u16* __restrict__ Wbf,
    const float* __restrict__ bk, const float* __restrict__ bv,
    u16* __restrict__ mhT, float* __restrict__ s1buf, float* __restrict__ s2buf,
    int b0, int BG) {
  __shared__ __align__(16) char ldsbuf[128 * 128 * 4];  // 64 KB: staging, then Cst
  u16* As = (u16*)ldsbuf;            // [128 t][32 f]
  u16* Bs = (u16*)(ldsbuf + 8192);   // [128 d][32 f]
  float* Cst = (float*)ldsbuf;       // [128 t][128 d] (reused after K-loop)
  int tid = threadIdx.x, lane = tid & 63, w = tid >> 6;
  int t0 = blockIdx.x * 128;
  int b_l = blockIdx.y / Hn, h = blockIdx.y % Hn, kv = blockIdx.z;
  int b = b0 + b_l;
  const u16* Abase = kv_raw + ((size_t)(kv * BG + b_l) * Hn + h) * TPn * Fn + (size_t)t0 * Fn;
  const u16* Bbase = Wbf + ((size_t)(kv * Hn + h)) * Dn * Fn;
  f32x4 acc[4][4];
#pragma unroll
  for (int mi = 0; mi < 4; ++mi)
#pragma unroll
    for (int ni = 0; ni < 4; ++ni) acc[mi][ni] = (f32x4){0.f, 0.f, 0.f, 0.f};
  int wm = (w >> 1) * 64, wn = (w & 1) * 64;
  for (int f0 = 0; f0 < Fn; f0 += 32) {
    __syncthreads();
#pragma unroll
    for (int r = 0; r < 2; ++r) {
      int lin = tid + r * 256;  // 0..511 : row=lin>>2 (128 rows), 16B part=lin&3
      int row = lin >> 2, part = lin & 3;
      *(float4*)((char*)As + lin * 16) = *(const float4*)(Abase + (size_t)row * Fn + f0 + part * 8);
      *(float4*)((char*)Bs + lin * 16) = *(const float4*)(Bbase + (size_t)row * Fn + f0 + part * 8);
    }
    __syncthreads();
    bf16x8 af[4], bg[4];
#pragma unroll
    for (int mi = 0; mi < 4; ++mi)
      af[mi] = *(const bf16x8*)(As + (wm + mi * 16 + (lane & 15)) * 32 + (lane >> 4) * 8);
#pragma unroll
    for (int ni = 0; ni < 4; ++ni)
      bg[ni] = *(const bf16x8*)(Bs + (wn + ni * 16 + (lane & 15)) * 32 + (lane >> 4) * 8);
#pragma unroll
    for (int mi = 0; mi < 4; ++mi)
#pragma unroll
      for (int ni = 0; ni < 4; ++ni)
        acc[mi][ni] = __builtin_amdgcn_mfma_f32_16x16x32_bf16(af[mi], bg[ni], acc[mi][ni], 0, 0, 0);
  }
  float bias[4];
  const float* bptr = (kv ? bv : bk) + h * Dn;
#pragma unroll
  for (int ni = 0; ni < 4; ++ni) bias[ni] = bptr[wn + ni * 16 + (lane & 15)];
  __syncthreads();
#pragma unroll
  for (int mi = 0; mi < 4; ++mi)
#pragma unroll
    for (int ni = 0; ni < 4; ++ni)
#pragma unroll
      for (int r = 0; r < 4; ++r) {
        int row = wm + mi * 16 + (lane >> 4) * 4 + r;  // t
        int col = wn + ni * 16 + (lane & 15);          // d
        Cst[row * 128 + col] = acc[mi][ni][r] + bias[ni];
      }
  __syncthreads();
  int d = tid >> 1, half = tid & 1;
  u16* orow = mhT + (((size_t)(kv * Bn + b) * Hn + h) * Dn + d) * TPn + t0;
  float ssum = 0.f, ssq = 0.f;
#pragma unroll
  for (int j = 0; j < 8; ++j) {
    int tb = half * 64 + j * 8;
    u16 pk[8];
#pragma unroll
    for (int ii = 0; ii < 8; ++ii) {
      int tl = tb + ii;
      float v = (t0 + tl < Tn) ? Cst[tl * 128 + d] : 0.f;
      u16 ub = f2bf(v);
      pk[ii] = ub;
      if (t0 + tl < Tn) { float vr = bf2f(ub); ssum += vr; ssq += vr * vr; }
    }
    uint4 v4;
    v4.x = (unsigned)pk[0] | ((unsigned)pk[1] << 16);
    v4.y = (unsigned)pk[2] | ((unsigned)pk[3] << 16);
    v4.z = (unsigned)pk[4] | ((unsigned)pk[5] << 16);
    v4.w = (unsigned)pk[6] | ((unsigned)pk[7] << 16);
    *reinterpret_cast<uint4*>(orow + tb) = v4;
  }
  int sidx = ((kv * Bn + b) * Hn + h) * Dn + d;
  atomicAdd(&s1buf[sidx], ssum);
  atomicAdd(&s2buf[sidx], ssq);
}

// ---------------------------------------------------------------- k3: attention
// one block per (b,h): scores -> softmax -> o1
__global__ __launch_bounds__(256) void k3_attn(
    const u16* __restrict__ mhT, const float* __restrict__ q, float* __restrict__ o1) {
  __shared__ float sc[TPn];
  __shared__ float qs[Dn];
  __shared__ float red[256];
  int tid = threadIdx.x;
  int b = blockIdx.x / Hn, h = blockIdx.x % Hn;
  const u16* K = mhT + ((size_t)(0 * Bn + b) * Hn + h) * Dn * TPn;
  const u16* V = mhT + ((size_t)(1 * Bn + b) * Hn + h) * Dn * TPn;
  if (tid < Dn) qs[tid] = q[h * Dn + tid];
  __syncthreads();
  const float scale = 0.088388347648318447f;  // 1/sqrt(128)
#pragma unroll
  for (int k = 0; k < 4; ++k) {
    int t = tid + k * 256;
    if (t < Tn) {
      float s = 0.f;
      for (int dd = 0; dd < Dn; ++dd) s += qs[dd] * bf2f(K[(size_t)dd * TPn + t]);
      sc[t] = s * scale;
    } else sc[t] = -1e30f;
  }
  __syncthreads();
  float m = -1e30f;
#pragma unroll
  for (int k = 0; k < 4; ++k) m = fmaxf(m, sc[tid + k * 256]);
  red[tid] = m;
  __syncthreads();
  for (int s = 128; s > 0; s >>= 1) { if (tid < s) red[tid] = fmaxf(red[tid], red[tid + s]); __syncthreads(); }
  m = red[0];
  __syncthreads();
  float lsum = 0.f;
#pragma unroll
  for (int k = 0; k < 4; ++k) {
    int t = tid + k * 256;
    float e = (t < Tn) ? __expf(sc[t] - m) : 0.f;
    sc[t] = e;
    lsum += e;
  }
  red[tid] = lsum;
  __syncthreads();
  for (int s = 128; s > 0; s >>= 1) { if (tid < s) red[tid] += red[tid + s]; __syncthreads(); }
  float inv = 1.f / red[0];
  __syncthreads();
  int d = tid & 127, half = tid >> 7;
  const u16* Vr = V + (size_t)d * TPn + half * 512;
  const float* at = sc + half * 512;
  float a = 0.f;
  for (int t = 0; t < 512; ++t) a += at[t] * bf2f(Vr[t]);
  red[tid] = a;
  __syncthreads();
  if (tid < 128) o1[((size_t)b * Hn + h) * Dn + tid] = inv * (red[tid] + red[tid + 128]);
}

// ---------------------------------------------------------------- k4: corr Gram
// S[k][l] = sum_t mh_k[t][k]*mh_v[t][l] via MFMA on [d][t] layout; then
// corr = (S - T*mu*nu)/(T*sd_k*sd_l), triu(k<l) -> packed mh_corr
__global__ __launch_bounds__(256) void k4_corr(
    const u16* __restrict__ mhT, const float* __restrict__ s1buf,
    const float* __restrict__ s2buf, float* __restrict__ corr) {
  __shared__ __align__(16) u16 As[128 * 32];
  __shared__ __align__(16) u16 Bs[128 * 32];
  __shared__ float mk[Dn], sk[Dn], mv[Dn], sv[Dn];
  int tid = threadIdx.x, lane = tid & 63, w = tid >> 6;
  int b = blockIdx.x / Hn, h = blockIdx.x % Hn;
  const u16* Kb = mhT + ((size_t)(0 * Bn + b) * Hn + h) * Dn * TPn;
  const u16* Vb = mhT + ((size_t)(1 * Bn + b) * Hn + h) * Dn * TPn;
  {
    int kv = tid >> 7, d = tid & 127;
    int sidx = ((kv * Bn + b) * Hn + h) * Dn + d;
    float a1 = s1buf[sidx], a2 = s2buf[sidx];
    float mu = a1 / (float)Tn;
    float var = (a2 - a1 * a1 / (float)Tn) / (float)(Tn - 1);
    float sd = sqrtf(fmaxf(var, 0.f)) + 1e-9f;
    if (kv == 0) { mk[d] = mu; sk[d] = sd; } else { mv[d] = mu; sv[d] = sd; }
  }
  f32x4 acc[4][4];
#pragma unroll
  for (int mi = 0; mi < 4; ++mi)
#pragma unroll
    for (int ni = 0; ni < 4; ++ni) acc[mi][ni] = (f32x4){0.f, 0.f, 0.f, 0.f};
  int wm = (w >> 1) * 64, wn = (w & 1) * 64;
  for (int t0 = 0; t0 < TPn; t0 += 32) {
    __syncthreads();
#pragma unroll
    for (int r = 0; r < 2; ++r) {
      int lin = tid + r * 256;
      int row = lin >> 2, part = lin & 3;
      *(float4*)((char*)As + lin * 16) = *(const float4*)(Kb + (size_t)row * TPn + t0 + part * 8);
      *(float4*)((char*)Bs + lin * 16) = *(const float4*)(Vb + (size_t)row * TPn + t0 + part * 8);
    }
    __syncthreads();
    bf16x8 af[4], bg[4];
#pragma unroll
    for (int mi = 0; mi < 4; ++mi)
      af[mi] = *(const bf16x8*)(As + (wm + mi * 16 + (lane & 15)) * 32 + (lane >> 4) * 8);
#pragma unroll
    for (int ni = 0; ni < 4; ++ni)
      bg[ni] = *(const bf16x8*)(Bs + (wn + ni * 16 + (lane & 15)) * 32 + (lane >> 4) * 8);
#pragma unroll
    for (int mi = 0; mi < 4; ++mi)
#pragma unroll
      for (int ni = 0; ni < 4; ++ni)
        acc[mi][ni] = __builtin_amdgcn_mfma_f32_16x16x32_bf16(af[mi], bg[ni], acc[mi][ni], 0, 0, 0);
  }
  const float invT = 1.f / (float)Tn;
#pragma unroll
  for (int mi = 0; mi < 4; ++mi)
#pragma unroll
    for (int ni = 0; ni < 4; ++ni)
#pragma unroll
      for (int r = 0; r < 4; ++r) {
        int mm = wm + mi * 16 + (lane >> 4) * 4 + r;  // k-dim (from mh_k)
        int nn = wn + ni * 16 + (lane & 15);          // l-dim (from mh_v)
        if (nn > mm) {
          float S = acc[mi][ni][r];
          float cv = (S - (float)Tn * mk[mm] * mv[nn]) * invT / (sk[mm] * sv[nn]);
          int cidx = mm * (2 * Dn - mm - 1) / 2 + (nn - mm - 1);
          corr[((size_t)b * Hn + h) * NCOR + cidx] = cv;
        }
      }
}

// ---------------------------------------------------------------- k5a: head proj
__global__ __launch_bounds__(256) void k5_proj(
    const float* __restrict__ corr, const float* __restrict__ Wproj,
    const float* __restrict__ bproj, float* __restrict__ outs) {
  __shared__ float red[8 * 256];
  int tid = threadIdx.x;
  int e = blockIdx.x, h = blockIdx.y;
  const float* wp = Wproj + ((size_t)h * En + e) * NCOR;
  float acc[8];
#pragma unroll
  for (int b = 0; b < 8; ++b) acc[b] = 0.f;
  for (int c = tid; c < NCOR; c += 256) {
    float wv = wp[c];
#pragma unroll
    for (int b = 0; b < 8; ++b) acc[b] += corr[((size_t)b * Hn + h) * NCOR + c] * wv;
  }
#pragma unroll
  for (int b = 0; b < 8; ++b) red[b * 256 + tid] = acc[b];
  __syncthreads();
  for (int s = 128; s > 0; s >>= 1) {
    if (tid < s) {
#pragma unroll
      for (int b = 0; b < 8; ++b) red[b * 256 + tid] += red[b * 256 + tid + s];
    }
    __syncthreads();
  }
  if (tid < 8) outs[((size_t)tid * Hn + h) * En + e] = red[tid * 256] + bproj[h * En + e];
}

// ---------------------------------------------------------------- k5b: final mix
__global__ __launch_bounds__(256) void k5_final(
    const float* __restrict__ outs, const float* __restrict__ o1,
    const float* __restrict__ WT, const float* __restrict__ bT,
    const float* __restrict__ Wp, const float* __restrict__ bp,
    float* __restrict__ out) {
  __shared__ float os[2048];
  __shared__ float o1s[1024];
  __shared__ float redF[256], redT[256];
  int tid = threadIdx.x;
  int b = blockIdx.x >> 3, ic = blockIdx.x & 7;
  for (int i = tid; i < 2048; i += 256) os[i] = outs[(size_t)b * 2048 + i];
  for (int i = tid; i < 1024; i += 256) o1s[i] = o1[(size_t)b * 1024 + i];
  __syncthreads();
  int il = tid >> 3, slice = tid & 7;
  int i = ic * 32 + il;
  const float* wpr = Wp + (size_t)i * 2048;
  const float* wtr = WT + (size_t)i * 1024;
  float aF = 0.f, aT = 0.f;
  for (int kk = 0; kk < 256; ++kk) { int j = kk * 8 + slice; aF += os[j] * wpr[j]; }
  for (int kk = 0; kk < 128; ++kk) { int j = kk * 8 + slice; aT += o1s[j] * wtr[j]; }
  redF[tid] = aF; redT[tid] = aT;
  __syncthreads();
  for (int s = 4; s > 0; s >>= 1) {
    if (slice < s) { redF[tid] += redF[tid + s]; redT[tid] += redT[tid + s]; }
    __syncthreads();
  }
  if (slice == 0) {
    float oF = redF[tid] + bp[i];
    float oT = redT[tid] + bT[i];
    out[(size_t)b * En + i] = 0.5f * oF + 0.5f * oT;
  }
}

// ---------------------------------------------------------------- launch
extern "C" void kernel_launch(void* const* d_in, const int* in_sizes, int n_in,
                              void* d_out, int out_size, void* d_ws, size_t ws_size,
                              hipStream_t stream) {
  const float* x     = (const float*)d_in[0];
  const float* wk    = (const float*)d_in[1];
  const float* wv    = (const float*)d_in[2];
  const float* q     = (const float*)d_in[3];
  const float* Wk    = (const float*)d_in[4];
  const float* bk    = (const float*)d_in[5];
  const float* Wv    = (const float*)d_in[6];
  const float* bv    = (const float*)d_in[7];
  const float* Wproj = (const float*)d_in[8];
  const float* bproj = (const float*)d_in[9];
  const float* WT    = (const float*)d_in[10];
  const float* bT    = (const float*)d_in[11];
  const float* Wp    = (const float*)d_in[12];
  const float* bp    = (const float*)d_in[13];
  float* out = (float*)d_out;

  char* ws = (char*)d_ws;
  size_t off = 0;
  auto alloc = [&](size_t bytes) { size_t p = off; off += (bytes + 255) & ~(size_t)255; return p; };
  float* kvw  = (float*)(ws + alloc((size_t)2 * Hn * Ln * 4));
  u16*   Wbf  = (u16*)  (ws + alloc((size_t)2 * Hn * Dn * Fn * 2));
  u16*   mhT  = (u16*)  (ws + alloc((size_t)2 * Bn * Hn * Dn * TPn * 2));
  float* s1   = (float*)(ws + alloc((size_t)2 * Bn * Hn * Dn * 4));
  float* s2   = (float*)(ws + alloc((size_t)2 * Bn * Hn * Dn * 4));
  float* o1   = (float*)(ws + alloc((size_t)Bn * Hn * Dn * 4));
  float* corr = (float*)(ws + alloc((size_t)Bn * Hn * NCOR * 4));
  float* outs = (float*)(ws + alloc((size_t)Bn * Hn * En * 4));
  size_t fixed = off;
  size_t per_b = (size_t)2 * Hn * TPn * Fn * 2;  // kv_raw per batch: 24 MB
  int BG = 8;
  while (BG > 1 && fixed + (size_t)BG * per_b > ws_size) BG >>= 1;
  u16* kv_raw = (u16*)(ws + fixed);

  k0_prep<<<6144, 256, 0, stream>>>(wk, wv, Wk, Wv, kvw, Wbf, s1, s2);
  for (int b0 = 0; b0 < Bn; b0 += BG) {
    k1_raw<<<dim3(24, 32, BG), 256, 0, stream>>>(x, kvw, kv_raw, b0, BG);
    k2_gemm<<<dim3(8, Hn * BG, 2), 256, 0, stream>>>(kv_raw, Wbf, bk, bv, mhT, s1, s2, b0, BG);
  }
  k3_attn<<<64, 256, 0, stream>>>(mhT, q, o1);
  k4_corr<<<64, 256, 0, stream>>>(mhT, s1, s2, corr);
  k5_proj<<<dim3(En, Hn), 256, 0, stream>>>(corr, Wproj, bproj, outs);
  k5_final<<<64, 256, 0, stream>>>(outs, o1, WT, bT, Wp, bp, out);
}

// Round 2
// 702.680 us; speedup vs baseline: 1.3128x; 1.3128x over previous
//
#include <hip/hip_runtime.h>
#include <hip/hip_bf16.h>

#define Hn 8
#define Fn 768
#define Dn 128
#define En 256
#define Ln 13
#define Bn 8
#define Tn 1000
#define TPn 1024
#define NCOR 8128

typedef float f32x4 __attribute__((ext_vector_type(4)));
typedef __bf16 bf16x8 __attribute__((ext_vector_type(8)));
typedef unsigned short u16;

static __device__ __forceinline__ u16 f2bf(float f) {
  __hip_bfloat16 h = __float2bfloat16(f);
  return __builtin_bit_cast(u16, h);
}
static __device__ __forceinline__ float bf2f(u16 u) {
  return __bfloat162float(__builtin_bit_cast(__hip_bfloat16, u));
}

// async global->LDS, 16B per lane. LDS dest must be wave-uniform base; HW adds lane*16.
static __device__ __forceinline__ void gload_lds16(const u16* g, u16* lds_wave_base) {
  __builtin_amdgcn_global_load_lds(
      (const __attribute__((address_space(1))) unsigned int*)g,
      (__attribute__((address_space(3))) unsigned int*)lds_wave_base, 16, 0, 0);
}

// ---------------------------------------------------------------- k0: prep
__global__ __launch_bounds__(256) void k0_prep(
    const float* __restrict__ wk, const float* __restrict__ wv,
    const float* __restrict__ Wk, const float* __restrict__ Wv,
    float* __restrict__ kvw, u16* __restrict__ Wbf,
    float* __restrict__ s1, float* __restrict__ s2) {
  int gid = blockIdx.x * 256 + threadIdx.x;
  if (gid < 16) {
    int kv = gid >> 3, h = gid & 7;
    const float* w = (kv ? wv : wk) + h * Ln;
    float m = -1e30f;
    for (int l = 0; l < Ln; ++l) m = fmaxf(m, w[l]);
    float e[Ln], s = 0.f;
    for (int l = 0; l < Ln; ++l) { e[l] = expf(w[l] - m); s += e[l]; }
    for (int l = 0; l < Ln; ++l) kvw[(kv * Hn + h) * Ln + l] = e[l] / s;
  }
  int n = 2 * Hn * Dn * Fn;
  for (int i = gid; i < n; i += gridDim.x * 256) {
    float v = (i < Hn * Dn * Fn) ? Wk[i] : Wv[i - Hn * Dn * Fn];
    Wbf[i] = f2bf(v);
  }
  int ns = 2 * Bn * Hn * Dn;
  for (int i = gid; i < ns; i += gridDim.x * 256) { s1[i] = 0.f; s2[i] = 0.f; }
}

// ---------------------------------------------------------------- k1: l-reduce
// thread = (f-lane 0..31, t-quad 0..7): 13 float4 loads cover 4 consecutive t.
// res LDS [o][t][f+pad2] transpose; phase C: 4 lanes assemble one 64B row.
__global__ __launch_bounds__(256) void k1_raw(
    const float* __restrict__ x, const float* __restrict__ kvw_g,
    u16* __restrict__ kv_raw, int b0, int BG) {
  __shared__ float kvw[16 * Ln];
  __shared__ u16 res[16 * 32 * 34];  // 34816 B; row stride 34 (17 uints, odd)
  int tid = threadIdx.x;
  if (tid < 16 * Ln) kvw[tid] = kvw_g[tid];
  int f0 = blockIdx.x * 32, t0 = blockIdx.y * 32;
  int b_l = blockIdx.z, b = b0 + b_l;
  int fl = tid & 31, tq = tid >> 5;
  int tbase = t0 + tq * 4;
  bool valid = (tbase < Tn);  // Tn%4==0 -> quads never straddle
  float4 xq[13];
  if (valid) {
    const float4* xp = (const float4*)(x + ((size_t)(b * Fn + f0 + fl) * Tn + tbase) * Ln);
#pragma unroll
    for (int i = 0; i < 13; ++i) xq[i] = xp[i];
  }
  __syncthreads();
  const float* xf = (const float*)xq;
  for (int o = 0; o < 16; ++o) {
    float a0 = 0.f, a1 = 0.f, a2 = 0.f, a3 = 0.f;
    if (valid) {
#pragma unroll
      for (int l = 0; l < Ln; ++l) {
        float w = kvw[o * Ln + l];
        a0 += xf[l] * w;
        a1 += xf[Ln + l] * w;
        a2 += xf[2 * Ln + l] * w;
        a3 += xf[3 * Ln + l] * w;
      }
    }
    int rb = o * 1088 + tq * 4 * 34 + fl;
    res[rb] = f2bf(a0);
    res[rb + 34] = f2bf(a1);
    res[rb + 68] = f2bf(a2);
    res[rb + 102] = f2bf(a3);
  }
  __syncthreads();
  int part = tid & 3;
#pragma unroll
  for (int it = 0; it < 8; ++it) {
    int r = (tid >> 2) + it * 64;
    int o = r >> 5, tl = r & 31;
    int kv = o >> 3, h = o & 7;
    const u16* src = res + o * 1088 + tl * 34 + part * 8;
    uint4 v;
    v.x = *(const unsigned*)(src + 0);
    v.y = *(const unsigned*)(src + 2);
    v.z = *(const unsigned*)(src + 4);
    v.w = *(const unsigned*)(src + 6);
    u16* dst = kv_raw + (((size_t)(kv * BG + b_l) * Hn + h) * TPn + t0 + tl) * Fn + f0 + part * 8;
    *reinterpret_cast<uint4*>(dst) = v;
  }
}

// ---------------------------------------------------------------- k2: main GEMM
// 128x128 tile, BK=32, bf16 MFMA. async global->LDS staging. bf16 Cst (33KB).
__global__ __launch_bounds__(256) void k2_gemm(
    const u16* __restrict__ kv_raw, const u16* __restrict__ Wbf,
    const float* __restrict__ bk, const float* __restrict__ bv,
    u16* __restrict__ mhT, float* __restrict__ s1buf, float* __restrict__ s2buf,
    int b0, int BG) {
  __shared__ __align__(16) char ldsbuf[128 * 130 * 2];  // 33280 B
  u16* As = (u16*)ldsbuf;            // [128 t][32 f]
  u16* Bs = (u16*)(ldsbuf + 8192);   // [128 d][32 f]
  u16* Cst = (u16*)ldsbuf;           // [128 t][130] (reused after K-loop)
  int tid = threadIdx.x, lane = tid & 63, w = tid >> 6;
  int t0 = blockIdx.x * 128;
  int b_l = blockIdx.y / Hn, h = blockIdx.y % Hn, kv = blockIdx.z;
  int b = b0 + b_l;
  const u16* Abase = kv_raw + ((size_t)(kv * BG + b_l) * Hn + h) * TPn * Fn + (size_t)t0 * Fn;
  const u16* Bbase = Wbf + ((size_t)(kv * Hn + h)) * Dn * Fn;
  f32x4 acc[4][4];
#pragma unroll
  for (int mi = 0; mi < 4; ++mi)
#pragma unroll
    for (int ni = 0; ni < 4; ++ni) acc[mi][ni] = (f32x4){0.f, 0.f, 0.f, 0.f};
  int wm = (w >> 1) * 64, wn = (w & 1) * 64;
  int lin0 = tid, lin1 = tid + 256;
  int row0 = lin0 >> 2, part0 = lin0 & 3;
  int row1 = lin1 >> 2, part1 = lin1 & 3;
  int wb0 = (w * 64) * 8, wb1 = (256 + w * 64) * 8;  // wave-uniform LDS elem base
  for (int f0 = 0; f0 < Fn; f0 += 32) {
    __syncthreads();
    gload_lds16(Abase + (size_t)row0 * Fn + f0 + part0 * 8, As + wb0);
    gload_lds16(Abase + (size_t)row1 * Fn + f0 + part1 * 8, As + wb1);
    gload_lds16(Bbase + (size_t)row0 * Fn + f0 + part0 * 8, Bs + wb0);
    gload_lds16(Bbase + (size_t)row1 * Fn + f0 + part1 * 8, Bs + wb1);
    __syncthreads();
    bf16x8 af[4], bg[4];
#pragma unroll
    for (int mi = 0; mi < 4; ++mi)
      af[mi] = *(const bf16x8*)(As + (wm + mi * 16 + (lane & 15)) * 32 + (lane >> 4) * 8);
#pragma unroll
    for (int ni = 0; ni < 4; ++ni)
      bg[ni] = *(const bf16x8*)(Bs + (wn + ni * 16 + (lane & 15)) * 32 + (lane >> 4) * 8);
#pragma unroll
    for (int mi = 0; mi < 4; ++mi)
#pragma unroll
      for (int ni = 0; ni < 4; ++ni)
        acc[mi][ni] = __builtin_amdgcn_mfma_f32_16x16x32_bf16(af[mi], bg[ni], acc[mi][ni], 0, 0, 0);
  }
  float bias[4];
  const float* bptr = (kv ? bv : bk) + h * Dn;
#pragma unroll
  for (int ni = 0; ni < 4; ++ni) bias[ni] = bptr[wn + ni * 16 + (lane & 15)];
  __syncthreads();
#pragma unroll
  for (int mi = 0; mi < 4; ++mi)
#pragma unroll
    for (int ni = 0; ni < 4; ++ni)
#pragma unroll
      for (int r = 0; r < 4; ++r) {
        int row = wm + mi * 16 + (lane >> 4) * 4 + r;  // t-local
        int col = wn + ni * 16 + (lane & 15);          // d
        float v = acc[mi][ni][r] + bias[ni];
        if (t0 + row >= Tn) v = 0.f;                   // zero-pad rows (Gram-safe)
        Cst[row * 130 + col] = f2bf(v);
      }
  __syncthreads();
  int d = tid >> 1, half = tid & 1;
  u16* orow = mhT + (((size_t)(kv * Bn + b) * Hn + h) * Dn + d) * TPn + t0;
  float ssum = 0.f, ssq = 0.f;
#pragma unroll
  for (int j = 0; j < 8; ++j) {
    int tb = half * 64 + j * 8;
    u16 pk[8];
#pragma unroll
    for (int ii = 0; ii < 8; ++ii) {
      u16 ub = Cst[(tb + ii) * 130 + d];
      pk[ii] = ub;
      float vr = bf2f(ub);
      ssum += vr;
      ssq += vr * vr;
    }
    uint4 v4;
    v4.x = (unsigned)pk[0] | ((unsigned)pk[1] << 16);
    v4.y = (unsigned)pk[2] | ((unsigned)pk[3] << 16);
    v4.z = (unsigned)pk[4] | ((unsigned)pk[5] << 16);
    v4.w = (unsigned)pk[6] | ((unsigned)pk[7] << 16);
    *reinterpret_cast<uint4*>(orow + tb) = v4;
  }
  int sidx = ((kv * Bn + b) * Hn + h) * Dn + d;
  atomicAdd(&s1buf[sidx], ssum);
  atomicAdd(&s2buf[sidx], ssq);
}

// ---------------------------------------------------------------- k3: attention
__global__ __launch_bounds__(256) void k3_attn(
    const u16* __restrict__ mhT, const float* __restrict__ q, float* __restrict__ o1) {
  __shared__ float sc[TPn];
  __shared__ float qs[Dn];
  __shared__ float red[256];
  int tid = threadIdx.x;
  int b = blockIdx.x / Hn, h = blockIdx.x % Hn;
  const u16* K = mhT + ((size_t)(0 * Bn + b) * Hn + h) * Dn * TPn;
  const u16* V = mhT + ((size_t)(1 * Bn + b) * Hn + h) * Dn * TPn;
  if (tid < Dn) qs[tid] = q[h * Dn + tid];
  __syncthreads();
  const float scale = 0.088388347648318447f;  // 1/sqrt(128)
  int t4 = tid * 4;
  float s0 = 0.f, s1v = 0.f, s2v = 0.f, s3v = 0.f;
  for (int dd = 0; dd < Dn; ++dd) {
    ushort4 k4 = *(const ushort4*)(K + (size_t)dd * TPn + t4);
    float qv = qs[dd];
    s0 += qv * bf2f(k4.x);
    s1v += qv * bf2f(k4.y);
    s2v += qv * bf2f(k4.z);
    s3v += qv * bf2f(k4.w);
  }
  float z[4] = {s0 * scale, s1v * scale, s2v * scale, s3v * scale};
  float m = -1e30f;
#pragma unroll
  for (int j = 0; j < 4; ++j) {
    if (t4 + j >= Tn) z[j] = -1e30f;
    m = fmaxf(m, z[j]);
  }
  red[tid] = m;
  __syncthreads();
  for (int s = 128; s > 0; s >>= 1) { if (tid < s) red[tid] = fmaxf(red[tid], red[tid + s]); __syncthreads(); }
  m = red[0];
  __syncthreads();
  float lsum = 0.f;
#pragma unroll
  for (int j = 0; j < 4; ++j) {
    float e = (t4 + j < Tn) ? __expf(z[j] - m) : 0.f;
    sc[t4 + j] = e;
    lsum += e;
  }
  red[tid] = lsum;
  __syncthreads();
  for (int s = 128; s > 0; s >>= 1) { if (tid < s) red[tid] += red[tid + s]; __syncthreads(); }
  float inv = 1.f / red[0];
  __syncthreads();
  int d = tid >> 1, half = tid & 1;
  const u16* Vr = V + (size_t)d * TPn + half * 512;
  const float* at = sc + half * 512;
  float a = 0.f;
  for (int i = 0; i < 64; ++i) {
    bf16x8 vv = *(const bf16x8*)(Vr + i * 8);
#pragma unroll
    for (int j = 0; j < 8; ++j) a += at[i * 8 + j] * (float)vv[j];
  }
  red[tid] = a;
  __syncthreads();
  if (half == 0) o1[((size_t)b * Hn + h) * Dn + d] = inv * (red[tid] + red[tid + 1]);
}

// ---------------------------------------------------------------- k4: corr Gram
__global__ __launch_bounds__(256) void k4_corr(
    const u16* __restrict__ mhT, const float* __restrict__ s1buf,
    const float* __restrict__ s2buf, float* __restrict__ corr) {
  __shared__ __align__(16) u16 As[128 * 32];
  __shared__ __align__(16) u16 Bs[128 * 32];
  __shared__ float mk[Dn], sk[Dn], mv[Dn], sv[Dn];
  int tid = threadIdx.x, lane = tid & 63, w = tid >> 6;
  int b = blockIdx.x / Hn, h = blockIdx.x % Hn;
  const u16* Kb = mhT + ((size_t)(0 * Bn + b) * Hn + h) * Dn * TPn;
  const u16* Vb = mhT + ((size_t)(1 * Bn + b) * Hn + h) * Dn * TPn;
  {
    int kv = tid >> 7, d = tid & 127;
    int sidx = ((kv * Bn + b) * Hn + h) * Dn + d;
    float a1 = s1buf[sidx], a2 = s2buf[sidx];
    float mu = a1 / (float)Tn;
    float var = (a2 - a1 * a1 / (float)Tn) / (float)(Tn - 1);
    float sd = sqrtf(fmaxf(var, 0.f)) + 1e-9f;
    if (kv == 0) { mk[d] = mu; sk[d] = sd; } else { mv[d] = mu; sv[d] = sd; }
  }
  f32x4 acc[4][4];
#pragma unroll
  for (int mi = 0; mi < 4; ++mi)
#pragma unroll
    for (int ni = 0; ni < 4; ++ni) acc[mi][ni] = (f32x4){0.f, 0.f, 0.f, 0.f};
  int wm = (w >> 1) * 64, wn = (w & 1) * 64;
  int lin0 = tid, lin1 = tid + 256;
  int row0 = lin0 >> 2, part0 = lin0 & 3;
  int row1 = lin1 >> 2, part1 = lin1 & 3;
  int wb0 = (w * 64) * 8, wb1 = (256 + w * 64) * 8;
  for (int t0 = 0; t0 < TPn; t0 += 32) {
    __syncthreads();
    gload_lds16(Kb + (size_t)row0 * TPn + t0 + part0 * 8, As + wb0);
    gload_lds16(Kb + (size_t)row1 * TPn + t0 + part1 * 8, As + wb1);
    gload_lds16(Vb + (size_t)row0 * TPn + t0 + part0 * 8, Bs + wb0);
    gload_lds16(Vb + (size_t)row1 * TPn + t0 + part1 * 8, Bs + wb1);
    __syncthreads();
    bf16x8 af[4], bg[4];
#pragma unroll
    for (int mi = 0; mi < 4; ++mi)
      af[mi] = *(const bf16x8*)(As + (wm + mi * 16 + (lane & 15)) * 32 + (lane >> 4) * 8);
#pragma unroll
    for (int ni = 0; ni < 4; ++ni)
      bg[ni] = *(const bf16x8*)(Bs + (wn + ni * 16 + (lane & 15)) * 32 + (lane >> 4) * 8);
#pragma unroll
    for (int mi = 0; mi < 4; ++mi)
#pragma unroll
      for (int ni = 0; ni < 4; ++ni)
        acc[mi][ni] = __builtin_amdgcn_mfma_f32_16x16x32_bf16(af[mi], bg[ni], acc[mi][ni], 0, 0, 0);
  }
  const float invT = 1.f / (float)Tn;
#pragma unroll
  for (int mi = 0; mi < 4; ++mi)
#pragma unroll
    for (int ni = 0; ni < 4; ++ni)
#pragma unroll
      for (int r = 0; r < 4; ++r) {
        int mm = wm + mi * 16 + (lane >> 4) * 4 + r;
        int nn = wn + ni * 16 + (lane & 15);
        if (nn > mm) {
          float S = acc[mi][ni][r];
          float cv = (S - (float)Tn * mk[mm] * mv[nn]) * invT / (sk[mm] * sv[nn]);
          int cidx = mm * (2 * Dn - mm - 1) / 2 + (nn - mm - 1);
          corr[((size_t)b * Hn + h) * NCOR + cidx] = cv;
        }
      }
}

// ---------------------------------------------------------------- k5a: head proj
__global__ __launch_bounds__(256) void k5_proj(
    const float* __restrict__ corr, const float* __restrict__ Wproj,
    const float* __restrict__ bproj, float* __restrict__ outs) {
  __shared__ float red[8 * 256];
  int tid = threadIdx.x;
  int e = blockIdx.x, h = blockIdx.y;
  const float4* wp4 = (const float4*)(Wproj + ((size_t)h * En + e) * NCOR);
  float accs[8];
#pragma unroll
  for (int b = 0; b < 8; ++b) accs[b] = 0.f;
  for (int k = 0; k < 8; ++k) {
    int c4 = tid + k * 256;
    if (c4 < NCOR / 4) {
      float4 wv = wp4[c4];
#pragma unroll
      for (int b = 0; b < 8; ++b) {
        float4 cv = *((const float4*)(corr + ((size_t)b * Hn + h) * NCOR) + c4);
        accs[b] += wv.x * cv.x + wv.y * cv.y + wv.z * cv.z + wv.w * cv.w;
      }
    }
  }
#pragma unroll
  for (int b = 0; b < 8; ++b) red[b * 256 + tid] = accs[b];
  __syncthreads();
  for (int s = 128; s > 0; s >>= 1) {
    if (tid < s) {
#pragma unroll
      for (int b = 0; b < 8; ++b) red[b * 256 + tid] += red[b * 256 + tid + s];
    }
    __syncthreads();
  }
  if (tid < 8) outs[((size_t)tid * Hn + h) * En + e] = red[tid * 256] + bproj[h * En + e];
}

// ---------------------------------------------------------------- k5b: final mix
__global__ __launch_bounds__(256) void k5_final(
    const float* __restrict__ outs, const float* __restrict__ o1,
    const float* __restrict__ WT, const float* __restrict__ bT,
    const float* __restrict__ Wp, const float* __restrict__ bp,
    float* __restrict__ out) {
  __shared__ float os[2048];
  __shared__ float o1s[1024];
  __shared__ float redF[256], redT[256];
  int tid = threadIdx.x;
  int b = blockIdx.x >> 3, ic = blockIdx.x & 7;
  for (int i = tid; i < 2048; i += 256) os[i] = outs[(size_t)b * 2048 + i];
  for (int i = tid; i < 1024; i += 256) o1s[i] = o1[(size_t)b * 1024 + i];
  __syncthreads();
  int il = tid >> 3, slice = tid & 7;
  int i = ic * 32 + il;
  const float* wpr = Wp + (size_t)i * 2048;
  const float* wtr = WT + (size_t)i * 1024;
  float aF = 0.f, aT = 0.f;
  for (int kk = 0; kk < 256; ++kk) { int j = kk * 8 + slice; aF += os[j] * wpr[j]; }
  for (int kk = 0; kk < 128; ++kk) { int j = kk * 8 + slice; aT += o1s[j] * wtr[j]; }
  redF[tid] = aF; redT[tid] = aT;
  __syncthreads();
  for (int s = 4; s > 0; s >>= 1) {
    if (slice < s) { redF[tid] += redF[tid + s]; redT[tid] += redT[tid + s]; }
    __syncthreads();
  }
  if (slice == 0) {
    float oF = redF[tid] + bp[i];
    float oT = redT[tid] + bT[i];
    out[(size_t)b * En + i] = 0.5f * oF + 0.5f * oT;
  }
}

// ---------------------------------------------------------------- launch
extern "C" void kernel_launch(void* const* d_in, const int* in_sizes, int n_in,
                              void* d_out, int out_size, void* d_ws, size_t ws_size,
                              hipStream_t stream) {
  const float* x     = (const float*)d_in[0];
  const float* wk    = (const float*)d_in[1];
  const float* wv    = (const float*)d_in[2];
  const float* q     = (const float*)d_in[3];
  const float* Wk    = (const float*)d_in[4];
  const float* bk    = (const float*)d_in[5];
  const float* Wv    = (const float*)d_in[6];
  const float* bv    = (const float*)d_in[7];
  const float* Wproj = (const float*)d_in[8];
  const float* bproj = (const float*)d_in[9];
  const float* WT    = (const float*)d_in[10];
  const float* bT    = (const float*)d_in[11];
  const float* Wp    = (const float*)d_in[12];
  const float* bp    = (const float*)d_in[13];
  float* out = (float*)d_out;

  char* ws = (char*)d_ws;
  size_t off = 0;
  auto alloc = [&](size_t bytes) { size_t p = off; off += (bytes + 255) & ~(size_t)255; return p; };
  float* kvw  = (float*)(ws + alloc((size_t)2 * Hn * Ln * 4));
  u16*   Wbf  = (u16*)  (ws + alloc((size_t)2 * Hn * Dn * Fn * 2));
  u16*   mhT  = (u16*)  (ws + alloc((size_t)2 * Bn * Hn * Dn * TPn * 2));
  float* s1   = (float*)(ws + alloc((size_t)2 * Bn * Hn * Dn * 4));
  float* s2   = (float*)(ws + alloc((size_t)2 * Bn * Hn * Dn * 4));
  float* o1   = (float*)(ws + alloc((size_t)Bn * Hn * Dn * 4));
  float* corr = (float*)(ws + alloc((size_t)Bn * Hn * NCOR * 4));
  float* outs = (float*)(ws + alloc((size_t)Bn * Hn * En * 4));
  size_t fixed = off;
  size_t per_b = (size_t)2 * Hn * TPn * Fn * 2;  // kv_raw per batch: 24 MB
  int BG = 8;
  while (BG > 1 && fixed + (size_t)BG * per_b > ws_size) BG >>= 1;
  u16* kv_raw = (u16*)(ws + fixed);

  k0_prep<<<6144, 256, 0, stream>>>(wk, wv, Wk, Wv, kvw, Wbf, s1, s2);
  for (int b0 = 0; b0 < Bn; b0 += BG) {
    k1_raw<<<dim3(24, 32, BG), 256, 0, stream>>>(x, kvw, kv_raw, b0, BG);
    k2_gemm<<<dim3(8, Hn * BG, 2), 256, 0, stream>>>(kv_raw, Wbf, bk, bv, mhT, s1, s2, b0, BG);
  }
  k3_attn<<<64, 256, 0, stream>>>(mhT, q, o1);
  k4_corr<<<64, 256, 0, stream>>>(mhT, s1, s2, corr);
  k5_proj<<<dim3(En, Hn), 256, 0, stream>>>(corr, Wproj, bproj, outs);
  k5_final<<<64, 256, 0, stream>>>(outs, o1, WT, bT, Wp, bp, out);
}